// Round 14
// baseline (162.559 us; speedup 1.0000x reference)
//
#include <hip/hip_runtime.h>
#include <math.h>

// Round 26: qkv re-tiled BM=128 x BN=64 with 32x64-per-wave -> grid (32,36)
// = 1152 blocks = 18 waves/CU (2x latency hiding for the ~52us latency-bound
// qkv). Unlike R23's failed 64x128 (which doubled B reads to 64x), this
// keeps B at 32 reads and doubles only A (6.3MB, per-XCD-stable slices,
// L2-hot). BN=64 = one head -> rope pairing (d,d+32) stays in-wave.
// Everything else identical to R25 (best config; flash = control).

typedef __bf16 bf16;
typedef __bf16 bf16x4 __attribute__((ext_vector_type(4)));
typedef __bf16 bf16x8 __attribute__((ext_vector_type(8)));
typedef float  f32x4  __attribute__((ext_vector_type(4)));

#define MFMA_BF16(a, b, c) __builtin_amdgcn_mfma_f32_16x16x32_bf16((a), (b), (c), 0, 0, 0)

#define SEQ  4096
#define NH   12
#define HD   64
#define DM   768
#define NQKV 2304
#define NPART 4
#define ATTN_SCALE 0.12f
#define LOG2E 1.4426950408889634f
#define RMS_EPS 1.1920928955078125e-07f

typedef __attribute__((address_space(3))) void  lds_void;
typedef const __attribute__((address_space(1))) void g_void;

__device__ __forceinline__ void gload16(const void* g, void* l)
{
  __builtin_amdgcn_global_load_lds((g_void*)g, (lds_void*)l, 16, 0, 0);
}

// ---------------------------------------------------------------------------
// One dispatch for all three f32->bf16 conversions.
// ---------------------------------------------------------------------------
__global__ __launch_bounds__(256) void convert_all(
    const float* __restrict__ s0, bf16* __restrict__ d0, int n0,
    const float* __restrict__ s1, bf16* __restrict__ d1, int n1,
    const float* __restrict__ s2, bf16* __restrict__ d2, int n2)
{
  int b = blockIdx.x;
  const int b0 = n0 >> 11, b1 = n1 >> 11;
  const float* s; bf16* d;
  if (b < b0)            { s = s0; d = d0; }
  else if (b < b0 + b1)  { s = s1; d = d1; b -= b0; }
  else                   { s = s2; d = d2; b -= b0 + b1; }
  const int i0 = (b * 256 + threadIdx.x) * 8;
  f32x4 a = *(const f32x4*)(s + i0);
  f32x4 c = *(const f32x4*)(s + i0 + 4);
  bf16x8 o;
#pragma unroll
  for (int j = 0; j < 4; j++) { o[j] = (bf16)a[j]; o[j + 4] = (bf16)c[j]; }
  *(bf16x8*)(d + i0) = o;
}

// ---------------------------------------------------------------------------
// QKV GEMM, BM=128 x BN=64, 4 waves of 32m x 64n each (18 waves/CU).
// 2-phase double-buffered gload_lds staging (3 loads/thread/iter).
// FUSED norm+rope epilogue for Q/K (V written transposed raw).
// Q gets ATTN_SCALE * LOG2E folded in so flash can use raw exp2f.
// ---------------------------------------------------------------------------
__global__ __launch_bounds__(256) void gemm_qkv(
    const bf16* __restrict__ A, const bf16* __restrict__ B,
    bf16* __restrict__ Qb, bf16* __restrict__ Kb, bf16* __restrict__ Vt)
{
  __shared__ bf16 As[2][128][32];
  __shared__ bf16 Bs[2][64][32];
  const int m0 = blockIdx.x * 128, n0 = blockIdx.y * 64;
  const int tid = threadIdx.x;
  const int lane = tid & 63, w = tid >> 6;
  const int c16 = lane & 15, q4 = lane >> 4;
  const int mo = w * 32;                             // wave = rows [mo, mo+32)
  const int srow = tid >> 2, scol = (tid & 3) * 8;   // LDS byte off = tid*16
  const f32x4 vzero = {0.f, 0.f, 0.f, 0.f};
  f32x4 acc[2][4];
#pragma unroll
  for (int i = 0; i < 2; i++)
#pragma unroll
    for (int j = 0; j < 4; j++) acc[i][j] = vzero;

  const bf16* aBase = A + (size_t)(m0 + srow) * DM + scol;
  const bf16* bBase = B + (size_t)(n0 + srow) * DM + scol;   // srow 0..63 used

#define STAGEQ(buf, kk) do {                                            \
    gload16(aBase + (kk),                   &As[buf][srow][scol]);      \
    gload16(aBase + (size_t)64 * DM + (kk), &As[buf][srow + 64][scol]); \
    gload16(bBase + (kk),                   &Bs[buf][srow][scol]);      \
  } while (0)

  STAGEQ(0, 0);
  __syncthreads();
  int cur = 0;
  for (int k0 = 0; k0 < DM; k0 += 32) {
    const int kn = k0 + 32;
    if (kn < DM) STAGEQ(cur ^ 1, kn);     // prefetch next tile (other buffer)
    bf16x8 ar[2], br[4];
#pragma unroll
    for (int mq = 0; mq < 2; mq++)
      ar[mq] = *(const bf16x8*)&As[cur][mo + mq * 16 + c16][q4 * 8];
#pragma unroll
    for (int nq = 0; nq < 4; nq++)
      br[nq] = *(const bf16x8*)&Bs[cur][nq * 16 + c16][q4 * 8];
    __builtin_amdgcn_s_setprio(1);
#pragma unroll
    for (int mq = 0; mq < 2; mq++)
#pragma unroll
      for (int nq = 0; nq < 4; nq++)
        acc[mq][nq] = MFMA_BF16(ar[mq], br[nq], acc[mq][nq]);
    __builtin_amdgcn_s_setprio(0);
    __syncthreads();                      // next tile landed; reads done
    cur ^= 1;
  }
#undef STAGEQ

  const int kidx = blockIdx.y / 12;       // 12 head-panels per matrix
  const int h = blockIdx.y - kidx * 12;

  if (kidx == 2) {
#pragma unroll
    for (int nq = 0; nq < 4; nq++) {
      const int d = nq * 16 + c16;
#pragma unroll
      for (int mq = 0; mq < 2; mq++) {
        const int mb = m0 + mo + mq * 16 + q4 * 4;
#pragma unroll
        for (int rg = 0; rg < 4; rg++)
          Vt[((h * HD) + d) * SEQ + mb + rg] = (bf16)acc[mq][nq][rg];
      }
    }
  } else {
    bf16* dst = kidx ? Kb : Qb;
    const float scale = kidx ? 1.0f : (ATTN_SCALE * LOG2E);
    const float fr = exp2f(-10.0f * (float)c16 * (1.0f / 15.0f));
#pragma unroll
    for (int mq = 0; mq < 2; mq++) {
#pragma unroll
      for (int rg = 0; rg < 4; rg++) {
        const int m = m0 + mo + mq * 16 + q4 * 4 + rg;
        const float x0 = acc[mq][0][rg], x1 = acc[mq][1][rg];
        const float x2 = acc[mq][2][rg], x3 = acc[mq][3][rg];
        float ss = x0 * x0 + x1 * x1 + x2 * x2 + x3 * x3;
        ss += __shfl_xor(ss, 1, 64);
        ss += __shfl_xor(ss, 2, 64);
        ss += __shfl_xor(ss, 4, 64);
        ss += __shfl_xor(ss, 8, 64);
        const float rinv = rsqrtf(ss * (1.0f / 64.0f) + RMS_EPS) * scale;
        const float xn0 = x0 * rinv, xn1 = x1 * rinv;
        const float xn2 = x2 * rinv, xn3 = x3 * rinv;
        float sn, cs;
        sincosf((float)m * fr, &sn, &cs);
        const float y0 = xn0 * cs + xn2 * sn;
        const float y2 = xn2 * cs - xn0 * sn;
        bf16* rp = dst + (size_t)(h * SEQ + m) * HD + c16;
        rp[0]  = (bf16)y0;
        rp[16] = (bf16)xn1;
        rp[32] = (bf16)y2;
        rp[48] = (bf16)xn3;
      }
    }
  }
}

// ---------------------------------------------------------------------------
// 64x64-tile proj GEMM, double-buffered 2-phase: 768 blocks = 3/CU.
// ---------------------------------------------------------------------------
__global__ __launch_bounds__(256) void gemm_proj(
    const bf16* __restrict__ A, const bf16* __restrict__ B, float* __restrict__ C)
{
  __shared__ bf16 As[2][64][32];
  __shared__ bf16 Bs[2][64][32];
  const int m0 = blockIdx.x * 64, n0 = blockIdx.y * 64;
  const int tid = threadIdx.x;
  const int lane = tid & 63, w = tid >> 6;
  const int c16 = lane & 15, q4 = lane >> 4;
  const int mo = (w & 1) * 32, no = (w >> 1) * 32;
  const int srow = tid >> 2, scol = (tid & 3) * 8;   // LDS byte off = tid*16
  const f32x4 vzero = {0.f, 0.f, 0.f, 0.f};
  f32x4 acc[2][2];
#pragma unroll
  for (int i = 0; i < 2; i++)
#pragma unroll
    for (int j = 0; j < 2; j++) acc[i][j] = vzero;

  const bf16* aBase = A + (size_t)(m0 + srow) * DM + scol;
  const bf16* bBase = B + (size_t)(n0 + srow) * DM + scol;

#define STAGE64(buf, kk) do {                          \
    gload16(aBase + (kk), &As[buf][srow][scol]);       \
    gload16(bBase + (kk), &Bs[buf][srow][scol]);       \
  } while (0)

  STAGE64(0, 0);
  __syncthreads();
  int cur = 0;
  for (int k0 = 0; k0 < DM; k0 += 32) {
    const int kn = k0 + 32;
    if (kn < DM) STAGE64(cur ^ 1, kn);
    bf16x8 ar[2], br[2];
#pragma unroll
    for (int mq = 0; mq < 2; mq++)
      ar[mq] = *(const bf16x8*)&As[cur][mo + mq * 16 + c16][q4 * 8];
#pragma unroll
    for (int nq = 0; nq < 2; nq++)
      br[nq] = *(const bf16x8*)&Bs[cur][no + nq * 16 + c16][q4 * 8];
    __builtin_amdgcn_s_setprio(1);
#pragma unroll
    for (int mq = 0; mq < 2; mq++)
#pragma unroll
      for (int nq = 0; nq < 2; nq++)
        acc[mq][nq] = MFMA_BF16(ar[mq], br[nq], acc[mq][nq]);
    __builtin_amdgcn_s_setprio(0);
    __syncthreads();
    cur ^= 1;
  }
#undef STAGE64

#pragma unroll
  for (int nq = 0; nq < 2; nq++) {
    const int n = n0 + no + nq * 16 + c16;
#pragma unroll
    for (int mq = 0; mq < 2; mq++) {
      const int mb = m0 + mo + mq * 16 + q4 * 4;
#pragma unroll
      for (int rg = 0; rg < 4; rg++)
        C[(size_t)(mb + rg) * DM + n] = acc[mq][nq][rg];
    }
  }
}

// ---------------------------------------------------------------------------
// Flash partial, BM=128, S^T orientation. 2-phase gload_lds staging
// (linear dest + pre-swizzled source), double-buffered, ONE __syncthreads
// per iter. l via ones-column MFMA. Wave-level dead-tile skip.
// 1D grid 768 = 8 XCDs x 96. (Unchanged from R25 — control.)
// ---------------------------------------------------------------------------
__global__ __launch_bounds__(256, 3) void flash_partial(
    const bf16* __restrict__ Qb, const bf16* __restrict__ Kb,
    const bf16* __restrict__ Vt, bf16* __restrict__ Opart,
    float* __restrict__ Lpart)
{
  __shared__ bf16 Ks[2][64][64];
  __shared__ bf16 Vts[2][64][64];
  __shared__ bf16 Pst[4][32][68];                 // [wave][q][s], 8B-pair conflict-free
  const int id = blockIdx.x;                      // 0..767
  const int swz = (id & 7) * 96 + (id >> 3);      // chunked XCD swizzle (768 = 8*96)
  const int h = swz >> 6;                         // 64 works per head (16*NPART)
  const int rrem = swz & 63;
  const int p = rrem >> 4;                        // 0..3
  const int jb = rrem & 15;                       // pair (31-jb, jb)
  const int tid = threadIdx.x;
  const int lane = tid & 63, w = tid >> 6;
  const int c16 = lane & 15, q4 = lane >> 4;
  const int sr = tid >> 3;                        // staging row 0..31
  const int scS = (((tid & 7) ^ (sr & 7))) * 8;   // pre-swizzled source col (bf16)
  const int sdst = (tid & 7) * 8;                 // linear LDS dest col (bf16)
  const int rsw = c16 & 7;                        // fragment-read row swizzle

  const bf16* Kbase = Kb + (size_t)h * SEQ * HD;
  const bf16* Vbase = Vt + (size_t)h * HD * SEQ;
  const f32x4 vzero = {0.f, 0.f, 0.f, 0.f};

#define FSTAGE(buf, ss) do {                                                   \
    gload16(&Kbase[(size_t)((ss) + sr) * HD + scS],       &Ks[buf][sr][sdst]); \
    gload16(&Kbase[(size_t)((ss) + sr + 32) * HD + scS],  &Ks[buf][sr + 32][sdst]); \
    gload16(&Vbase[(size_t)sr * SEQ + (ss) + scS],        &Vts[buf][sr][sdst]); \
    gload16(&Vbase[(size_t)(sr + 32) * SEQ + (ss) + scS], &Vts[buf][sr + 32][sdst]); \
  } while (0)

  // B-fragment = 1.0 in column n==0: row-sum extractor for l.
  const bf16 bv1c = (c16 == 0) ? (bf16)1.0f : (bf16)0.0f;
  bf16x8 bone;
#pragma unroll
  for (int e = 0; e < 8; e++) bone[e] = bv1c;

#pragma unroll 1
  for (int half = 0; half < 2; ++half) {
    const int qi = half ? jb : (31 - jb);         // heavy q-tile first
    const int q0 = qi * 128;

    bf16x8 aq[2][2];
#pragma unroll
    for (int f = 0; f < 2; f++) {
      const int tq = q0 + w * 32 + f * 16 + c16;
      aq[f][0] = *(const bf16x8*)&Qb[((h * SEQ) + tq) * HD + q4 * 8];
      aq[f][1] = *(const bf16x8*)&Qb[((h * SEQ) + tq) * HD + 32 + q4 * 8];
    }
    const int qg[2] = { q0 + w * 32 + c16, q0 + w * 32 + 16 + c16 };  // lane's q-row per f
    const int qb[2] = { q0 + w * 32,       q0 + w * 32 + 16 };        // wave-uniform min q-row
    const int wmax = q0 + w * 32 + 31;            // wave-uniform max q-row

    f32x4 O[2][4];
    f32x4 acc_l[2] = {vzero, vzero};
#pragma unroll
    for (int f = 0; f < 2; f++)
#pragma unroll
      for (int j = 0; j < 4; j++) O[f][j] = vzero;

    const int sEnd = q0 + 64;
    const int sBeg = p * 64;
    if (sBeg <= sEnd) {
      FSTAGE(0, sBeg);
      __syncthreads();                    // tile 0 landed (vmcnt drain)
      int cur = 0;

      for (int s0 = sBeg; s0 <= sEnd; s0 += NPART * 64) {
        const int snext = s0 + NPART * 64;
        if (snext <= sEnd) FSTAGE(cur ^ 1, snext);   // prefetch next tile

        if (s0 <= wmax) {                 // wave-uniform: tile has live rows
          // K fragments: A-operand [m=s][k=d], swizzled cols
          bf16x8 kf0[4], kf1[4];
#pragma unroll
          for (int nt = 0; nt < 4; nt++) {
            kf0[nt] = *(const bf16x8*)&Ks[cur][nt * 16 + c16][(q4 ^ rsw) * 8];
            kf1[nt] = *(const bf16x8*)&Ks[cur][nt * 16 + c16][((q4 + 4) ^ rsw) * 8];
          }
#pragma unroll
          for (int f = 0; f < 2; f++) {
            // S^T tile: D[m=s][n=q]; lane holds q=c16, s=nt*16+q4*4+rg
            f32x4 S[4];
            __builtin_amdgcn_s_setprio(1);
#pragma unroll
            for (int nt = 0; nt < 4; nt++) {
              f32x4 z = vzero;
              z = MFMA_BF16(kf0[nt], aq[f][0], z);
              z = MFMA_BF16(kf1[nt], aq[f][1], z);
              S[nt] = z;
            }
            __builtin_amdgcn_s_setprio(0);
            if (s0 + 63 <= qb[f]) {
              // interior tile: no lane of this wave/f is masked
#pragma unroll
              for (int nt = 0; nt < 4; nt++) {
#pragma unroll
                for (int rg = 0; rg < 4; rg++) S[nt][rg] = exp2f(S[nt][rg]);
                bf16x4 pk = { (bf16)S[nt][0], (bf16)S[nt][1], (bf16)S[nt][2], (bf16)S[nt][3] };
                *(bf16x4*)&Pst[w][f * 16 + c16][nt * 16 + q4 * 4] = pk;
              }
            } else if (s0 > qb[f] + 15) {
              // tile entirely above the diagonal for this wave/f: all masked
              const bf16x4 zk = { (bf16)0.f, (bf16)0.f, (bf16)0.f, (bf16)0.f };
#pragma unroll
              for (int nt = 0; nt < 4; nt++)
                *(bf16x4*)&Pst[w][f * 16 + c16][nt * 16 + q4 * 4] = zk;
            } else {
              // diagonal tile: per-element mask
#pragma unroll
              for (int nt = 0; nt < 4; nt++) {
#pragma unroll
                for (int rg = 0; rg < 4; rg++) {
                  const int s_g = s0 + nt * 16 + q4 * 4 + rg;
                  S[nt][rg] = (s_g > qg[f]) ? 0.f : exp2f(S[nt][rg]);
                }
                bf16x4 pk = { (bf16)S[nt][0], (bf16)S[nt][1], (bf16)S[nt][2], (bf16)S[nt][3] };
                *(bf16x4*)&Pst[w][f * 16 + c16][nt * 16 + q4 * 4] = pk;
              }
            }
          }
          // P fragments (A-op): contiguous b128 from Pst (wave-private)
          bf16x8 ap[2][2];
#pragma unroll
          for (int f = 0; f < 2; f++) {
            ap[f][0] = *(const bf16x8*)&Pst[w][f * 16 + c16][q4 * 8];
            ap[f][1] = *(const bf16x8*)&Pst[w][f * 16 + c16][32 + q4 * 8];
          }
          // row-sum l via ones-column MFMA (matrix pipe, not VALU)
#pragma unroll
          for (int f = 0; f < 2; f++) {
            acc_l[f] = MFMA_BF16(ap[f][0], bone, acc_l[f]);
            acc_l[f] = MFMA_BF16(ap[f][1], bone, acc_l[f]);
          }
#pragma unroll
          for (int dt = 0; dt < 4; dt++) {
            bf16x8 bv0 = *(const bf16x8*)&Vts[cur][dt * 16 + c16][(q4 ^ rsw) * 8];
            bf16x8 bw1 = *(const bf16x8*)&Vts[cur][dt * 16 + c16][((q4 + 4) ^ rsw) * 8];
            __builtin_amdgcn_s_setprio(1);
#pragma unroll
            for (int f = 0; f < 2; f++) {
              O[f][dt] = MFMA_BF16(ap[f][0], bv0, O[f][dt]);
              O[f][dt] = MFMA_BF16(ap[f][1], bw1, O[f][dt]);
            }
            __builtin_amdgcn_s_setprio(0);
          }
        }
        __syncthreads();                  // all waves: next tile landed; reads done
        cur ^= 1;
      }
    }

    const int u = ((h * 32 + qi) * NPART + p);
    bf16* Op = Opart + (size_t)u * 8192;            // 128 x 64
#pragma unroll
    for (int f = 0; f < 2; f++)
#pragma unroll
      for (int dt = 0; dt < 4; dt++)
#pragma unroll
        for (int rg = 0; rg < 4; rg++)
          Op[(w * 32 + f * 16 + q4 * 4 + rg) * 64 + dt * 16 + c16] = (bf16)O[f][dt][rg];
    // l lives in D[q][0]: lanes with c16==0, row q = q4*4+rg.
    if (c16 == 0) {
#pragma unroll
      for (int f = 0; f < 2; f++)
#pragma unroll
        for (int rg = 0; rg < 4; rg++)
          Lpart[u * 128 + w * 32 + f * 16 + q4 * 4 + rg] = acc_l[f][rg];
    }
  }
#undef FSTAGE
}

// ---------------------------------------------------------------------------
// Combine: Y = (sum_p O_p) / (sum_p l_p). Block per 64-row chunk x head.
// ---------------------------------------------------------------------------
__global__ __launch_bounds__(256) void flash_combine(
    const bf16* __restrict__ Opart, const float* __restrict__ Lpart,
    bf16* __restrict__ Y)
{
  const int q64 = blockIdx.x, h = blockIdx.y;
  const int qi = q64 >> 1, roff = (q64 & 1) * 64;
  const int row = threadIdx.x >> 2, cg = (threadIdx.x & 3) * 16;
  const int u0 = (h * 32 + qi) * NPART;
  const int r128 = roff + row;
  float lsum = 0.f;
#pragma unroll
  for (int p = 0; p < NPART; p++) lsum += Lpart[(u0 + p) * 128 + r128];
  const float inv = 1.0f / lsum;
  const bf16* O0 = Opart + (size_t)u0 * 8192 + r128 * 64 + cg;
  bf16* yp = Y + (size_t)(q64 * 64 + row) * DM + h * HD + cg;
#pragma unroll
  for (int j = 0; j < 16; j += 8) {
    float s[8] = {0, 0, 0, 0, 0, 0, 0, 0};
#pragma unroll
    for (int p = 0; p < NPART; p++) {
      bf16x8 a = *(const bf16x8*)(O0 + p * 8192 + j);
#pragma unroll
      for (int e = 0; e < 8; e++) s[e] += (float)a[e];
    }
#pragma unroll
    for (int e = 0; e < 8; e++) yp[j + e] = (bf16)(s[e] * inv);
  }
}

// ---------------------------------------------------------------------------
extern "C" void kernel_launch(void* const* d_in, const int* in_sizes, int n_in,
                              void* d_out, int out_size, void* d_ws, size_t ws_size,
                              hipStream_t stream)
{
  (void)in_sizes; (void)n_in; (void)out_size; (void)ws_size;
  const float* x      = (const float*)d_in[0];
  const float* qkvw   = (const float*)d_in[1];
  const float* cprojw = (const float*)d_in[2];
  float* outp = (float*)d_out;

  const int NX = SEQ * DM, NW = NQKV * DM, NP = DM * DM;

  char* ws = (char*)d_ws;
  bf16*  xb    = (bf16*)(ws);                       // 6,291,456
  bf16*  wqkv  = (bf16*)(ws + 6291456);             // 3,538,944
  bf16*  wproj = (bf16*)(ws + 9830400);             // 1,179,648
  bf16*  Q     = (bf16*)(ws + 11010048);            // 6,291,456
  bf16*  K     = (bf16*)(ws + 17301504);            // 6,291,456
  bf16*  Vt    = (bf16*)(ws + 23592960);            // 6,291,456
  bf16*  Y     = (bf16*)(ws + 29884416);            // 6,291,456
  bf16*  Opart = (bf16*)(ws + 36175872);            // 25,165,824 (1536 x 8192 bf16)
  float* Lpart = (float*)(ws + 61341696);           //    786,432  (total 62.1 MB)

  convert_all<<<dim3((NX + NW + NP) / 2048), 256, 0, stream>>>(
      x, xb, NX, qkvw, wqkv, NW, cprojw, wproj, NP);

  gemm_qkv     <<<dim3(SEQ / 128, NQKV / 64), 256, 0, stream>>>(xb, wqkv, Q, K, Vt);
  flash_partial<<<dim3(16 * NH * NPART),      256, 0, stream>>>(Q, K, Vt, Opart, Lpart);
  flash_combine<<<dim3(SEQ / 64, NH),         256, 0, stream>>>(Opart, Lpart, Y);
  gemm_proj    <<<dim3(SEQ / 64, DM / 64),    256, 0, stream>>>(Y, wproj, outp);
}

// Round 15
// 160.846 us; speedup vs baseline: 1.0107x; 1.0107x over previous
//
#include <hip/hip_runtime.h>
#include <math.h>

// Round 27: revert to R25 (best, 161.2; R26's qkv retile tested neutral-
// negative). One work-deletion added: ROPE LUT. qkv's epilogue was calling
// sincosf 8x/thread (~300+ VALU instr, one full K-iter worth, on the
// busiest pipe). convert_all now appends 256 blocks that precompute
// ropeT[m][c16] = (cos,sin)(m*fr(c16)) (4096x16 float2 = 512KB, L2-hot);
// epilogue replaces sincosf with one 8B load each (independent, hoisted).

typedef __bf16 bf16;
typedef __bf16 bf16x4 __attribute__((ext_vector_type(4)));
typedef __bf16 bf16x8 __attribute__((ext_vector_type(8)));
typedef float  f32x4  __attribute__((ext_vector_type(4)));

#define MFMA_BF16(a, b, c) __builtin_amdgcn_mfma_f32_16x16x32_bf16((a), (b), (c), 0, 0, 0)

#define SEQ  4096
#define NH   12
#define HD   64
#define DM   768
#define NQKV 2304
#define NPART 4
#define ATTN_SCALE 0.12f
#define LOG2E 1.4426950408889634f
#define RMS_EPS 1.1920928955078125e-07f

typedef __attribute__((address_space(3))) void  lds_void;
typedef const __attribute__((address_space(1))) void g_void;

__device__ __forceinline__ void gload16(const void* g, void* l)
{
  __builtin_amdgcn_global_load_lds((g_void*)g, (lds_void*)l, 16, 0, 0);
}

// ---------------------------------------------------------------------------
// One dispatch: three f32->bf16 conversions + rope LUT (last 256 blocks).
// ---------------------------------------------------------------------------
__global__ __launch_bounds__(256) void convert_all(
    const float* __restrict__ s0, bf16* __restrict__ d0, int n0,
    const float* __restrict__ s1, bf16* __restrict__ d1, int n1,
    const float* __restrict__ s2, bf16* __restrict__ d2, int n2,
    float2* __restrict__ ropeT)
{
  int b = blockIdx.x;
  const int b0 = n0 >> 11, b1 = n1 >> 11, b2 = n2 >> 11;
  if (b >= b0 + b1 + b2) {
    // rope LUT: idx = m*16 + c, m<4096, c<16
    const int idx = (b - (b0 + b1 + b2)) * 256 + threadIdx.x;
    const int m = idx >> 4, c = idx & 15;
    const float fr = exp2f(-10.0f * (float)c * (1.0f / 15.0f));
    float sn, cs;
    sincosf((float)m * fr, &sn, &cs);
    ropeT[idx] = make_float2(cs, sn);
    return;
  }
  const float* s; bf16* d;
  if (b < b0)            { s = s0; d = d0; }
  else if (b < b0 + b1)  { s = s1; d = d1; b -= b0; }
  else                   { s = s2; d = d2; b -= b0 + b1; }
  const int i0 = (b * 256 + threadIdx.x) * 8;
  f32x4 a = *(const f32x4*)(s + i0);
  f32x4 c = *(const f32x4*)(s + i0 + 4);
  bf16x8 o;
#pragma unroll
  for (int j = 0; j < 4; j++) { o[j] = (bf16)a[j]; o[j + 4] = (bf16)c[j]; }
  *(bf16x8*)(d + i0) = o;
}

// ---------------------------------------------------------------------------
// 128x128-tile GEMM core, double-buffered 2-phase (BK=32, 4 waves 2x2).
// ---------------------------------------------------------------------------
__device__ __forceinline__ void gemm128_core(
    const bf16* __restrict__ A, const bf16* __restrict__ B,
    int m0, int n0, bf16 (*As)[128][32], bf16 (*Bs)[128][32], f32x4 acc[4][4])
{
  const int tid = threadIdx.x;
  const int lane = tid & 63, w = tid >> 6;
  const int c16 = lane & 15, q4 = lane >> 4;
  const int mo = (w & 1) * 64, no = (w >> 1) * 64;
  const int srow = tid >> 2, scol = (tid & 3) * 8;   // LDS byte off = tid*16 (lane-linear)
  const f32x4 vzero = {0.f, 0.f, 0.f, 0.f};
#pragma unroll
  for (int i = 0; i < 4; i++)
#pragma unroll
    for (int j = 0; j < 4; j++) acc[i][j] = vzero;

  const bf16* aBase = A + (size_t)(m0 + srow) * DM + scol;
  const bf16* bBase = B + (size_t)(n0 + srow) * DM + scol;

#define STAGE128(buf, kk) do {                                          \
    gload16(aBase + (kk),                   &As[buf][srow][scol]);      \
    gload16(aBase + (size_t)64 * DM + (kk), &As[buf][srow + 64][scol]); \
    gload16(bBase + (kk),                   &Bs[buf][srow][scol]);      \
    gload16(bBase + (size_t)64 * DM + (kk), &Bs[buf][srow + 64][scol]); \
  } while (0)

  STAGE128(0, 0);
  __syncthreads();
  int cur = 0;
  for (int k0 = 0; k0 < DM; k0 += 32) {
    const int kn = k0 + 32;
    if (kn < DM) STAGE128(cur ^ 1, kn);   // prefetch next tile (other buffer)
    bf16x8 ar[4], br[4];
#pragma unroll
    for (int mq = 0; mq < 4; mq++)
      ar[mq] = *(const bf16x8*)&As[cur][mo + mq * 16 + c16][q4 * 8];
#pragma unroll
    for (int nq = 0; nq < 4; nq++)
      br[nq] = *(const bf16x8*)&Bs[cur][no + nq * 16 + c16][q4 * 8];
    __builtin_amdgcn_s_setprio(1);
#pragma unroll
    for (int mq = 0; mq < 4; mq++)
#pragma unroll
      for (int nq = 0; nq < 4; nq++)
        acc[mq][nq] = MFMA_BF16(ar[mq], br[nq], acc[mq][nq]);
    __builtin_amdgcn_s_setprio(0);
    __syncthreads();                      // next tile landed; reads done
    cur ^= 1;
  }
#undef STAGE128
}

// QKV GEMM with FUSED norm+rope epilogue for Q/K (V written transposed raw).
// Q gets ATTN_SCALE * LOG2E folded in so flash can use raw exp2f.
// rope angles from precomputed LUT (one 8B load replaces sincosf).
__global__ __launch_bounds__(256) void gemm_qkv(
    const bf16* __restrict__ A, const bf16* __restrict__ B,
    bf16* __restrict__ Qb, bf16* __restrict__ Kb, bf16* __restrict__ Vt,
    const float2* __restrict__ ropeT)
{
  __shared__ bf16 As[2][128][32];
  __shared__ bf16 Bs[2][128][32];
  const int m0 = blockIdx.x * 128, n0 = blockIdx.y * 128;
  f32x4 acc[4][4];
  gemm128_core(A, B, m0, n0, As, Bs, acc);

  const int lane = threadIdx.x & 63, w = threadIdx.x >> 6;
  const int c16 = lane & 15, q4 = lane >> 4;
  const int mo = (w & 1) * 64, no = (w >> 1) * 64;
  const int kidx = blockIdx.y / 6;
  const int rr0 = (n0 - kidx * DM) + no;     // multiple of 64: one full head
  const int h = rr0 >> 6;

  if (kidx == 2) {
#pragma unroll
    for (int nq = 0; nq < 4; nq++) {
      const int d = nq * 16 + c16;
#pragma unroll
      for (int mq = 0; mq < 4; mq++) {
        const int mb = m0 + mo + mq * 16 + q4 * 4;
#pragma unroll
        for (int rg = 0; rg < 4; rg++)
          Vt[((h * HD) + d) * SEQ + mb + rg] = (bf16)acc[mq][nq][rg];
      }
    }
  } else {
    bf16* dst = kidx ? Kb : Qb;
    const float scale = kidx ? 1.0f : (ATTN_SCALE * LOG2E);
#pragma unroll
    for (int mq = 0; mq < 4; mq++) {
#pragma unroll
      for (int rg = 0; rg < 4; rg++) {
        const int m = m0 + mo + mq * 16 + q4 * 4 + rg;
        const float x0 = acc[mq][0][rg], x1 = acc[mq][1][rg];
        const float x2 = acc[mq][2][rg], x3 = acc[mq][3][rg];
        float ss = x0 * x0 + x1 * x1 + x2 * x2 + x3 * x3;
        ss += __shfl_xor(ss, 1, 64);
        ss += __shfl_xor(ss, 2, 64);
        ss += __shfl_xor(ss, 4, 64);
        ss += __shfl_xor(ss, 8, 64);
        const float rinv = rsqrtf(ss * (1.0f / 64.0f) + RMS_EPS) * scale;
        const float xn0 = x0 * rinv, xn1 = x1 * rinv;
        const float xn2 = x2 * rinv, xn3 = x3 * rinv;
        const float2 t = ropeT[(m << 4) | c16];
        const float cs = t.x, sn = t.y;
        const float y0 = xn0 * cs + xn2 * sn;
        const float y2 = xn2 * cs - xn0 * sn;
        bf16* rp = dst + (size_t)(h * SEQ + m) * HD + c16;
        rp[0]  = (bf16)y0;
        rp[16] = (bf16)xn1;
        rp[32] = (bf16)y2;
        rp[48] = (bf16)xn3;
      }
    }
  }
}

// ---------------------------------------------------------------------------
// 64x64-tile proj GEMM, double-buffered 2-phase: 768 blocks = 3/CU.
// ---------------------------------------------------------------------------
__global__ __launch_bounds__(256) void gemm_proj(
    const bf16* __restrict__ A, const bf16* __restrict__ B, float* __restrict__ C)
{
  __shared__ bf16 As[2][64][32];
  __shared__ bf16 Bs[2][64][32];
  const int m0 = blockIdx.x * 64, n0 = blockIdx.y * 64;
  const int tid = threadIdx.x;
  const int lane = tid & 63, w = tid >> 6;
  const int c16 = lane & 15, q4 = lane >> 4;
  const int mo = (w & 1) * 32, no = (w >> 1) * 32;
  const int srow = tid >> 2, scol = (tid & 3) * 8;   // LDS byte off = tid*16
  const f32x4 vzero = {0.f, 0.f, 0.f, 0.f};
  f32x4 acc[2][2];
#pragma unroll
  for (int i = 0; i < 2; i++)
#pragma unroll
    for (int j = 0; j < 2; j++) acc[i][j] = vzero;

  const bf16* aBase = A + (size_t)(m0 + srow) * DM + scol;
  const bf16* bBase = B + (size_t)(n0 + srow) * DM + scol;

#define STAGE64(buf, kk) do {                          \
    gload16(aBase + (kk), &As[buf][srow][scol]);       \
    gload16(bBase + (kk), &Bs[buf][srow][scol]);       \
  } while (0)

  STAGE64(0, 0);
  __syncthreads();
  int cur = 0;
  for (int k0 = 0; k0 < DM; k0 += 32) {
    const int kn = k0 + 32;
    if (kn < DM) STAGE64(cur ^ 1, kn);
    bf16x8 ar[2], br[2];
#pragma unroll
    for (int mq = 0; mq < 2; mq++)
      ar[mq] = *(const bf16x8*)&As[cur][mo + mq * 16 + c16][q4 * 8];
#pragma unroll
    for (int nq = 0; nq < 2; nq++)
      br[nq] = *(const bf16x8*)&Bs[cur][no + nq * 16 + c16][q4 * 8];
    __builtin_amdgcn_s_setprio(1);
#pragma unroll
    for (int mq = 0; mq < 2; mq++)
#pragma unroll
      for (int nq = 0; nq < 2; nq++)
        acc[mq][nq] = MFMA_BF16(ar[mq], br[nq], acc[mq][nq]);
    __builtin_amdgcn_s_setprio(0);
    __syncthreads();
    cur ^= 1;
  }
#undef STAGE64

#pragma unroll
  for (int nq = 0; nq < 2; nq++) {
    const int n = n0 + no + nq * 16 + c16;
#pragma unroll
    for (int mq = 0; mq < 2; mq++) {
      const int mb = m0 + mo + mq * 16 + q4 * 4;
#pragma unroll
      for (int rg = 0; rg < 4; rg++)
        C[(size_t)(mb + rg) * DM + n] = acc[mq][nq][rg];
    }
  }
}

// ---------------------------------------------------------------------------
// Flash partial, BM=128, S^T orientation. 2-phase gload_lds staging
// (linear dest + pre-swizzled source), double-buffered, ONE __syncthreads
// per iter. l via ones-column MFMA. Wave-level dead-tile skip.
// 1D grid 768 = 8 XCDs x 96. (Unchanged from R25.)
// ---------------------------------------------------------------------------
__global__ __launch_bounds__(256, 3) void flash_partial(
    const bf16* __restrict__ Qb, const bf16* __restrict__ Kb,
    const bf16* __restrict__ Vt, bf16* __restrict__ Opart,
    float* __restrict__ Lpart)
{
  __shared__ bf16 Ks[2][64][64];
  __shared__ bf16 Vts[2][64][64];
  __shared__ bf16 Pst[4][32][68];                 // [wave][q][s], 8B-pair conflict-free
  const int id = blockIdx.x;                      // 0..767
  const int swz = (id & 7) * 96 + (id >> 3);      // chunked XCD swizzle (768 = 8*96)
  const int h = swz >> 6;                         // 64 works per head (16*NPART)
  const int rrem = swz & 63;
  const int p = rrem >> 4;                        // 0..3
  const int jb = rrem & 15;                       // pair (31-jb, jb)
  const int tid = threadIdx.x;
  const int lane = tid & 63, w = tid >> 6;
  const int c16 = lane & 15, q4 = lane >> 4;
  const int sr = tid >> 3;                        // staging row 0..31
  const int scS = (((tid & 7) ^ (sr & 7))) * 8;   // pre-swizzled source col (bf16)
  const int sdst = (tid & 7) * 8;                 // linear LDS dest col (bf16)
  const int rsw = c16 & 7;                        // fragment-read row swizzle

  const bf16* Kbase = Kb + (size_t)h * SEQ * HD;
  const bf16* Vbase = Vt + (size_t)h * HD * SEQ;
  const f32x4 vzero = {0.f, 0.f, 0.f, 0.f};

#define FSTAGE(buf, ss) do {                                                   \
    gload16(&Kbase[(size_t)((ss) + sr) * HD + scS],       &Ks[buf][sr][sdst]); \
    gload16(&Kbase[(size_t)((ss) + sr + 32) * HD + scS],  &Ks[buf][sr + 32][sdst]); \
    gload16(&Vbase[(size_t)sr * SEQ + (ss) + scS],        &Vts[buf][sr][sdst]); \
    gload16(&Vbase[(size_t)(sr + 32) * SEQ + (ss) + scS], &Vts[buf][sr + 32][sdst]); \
  } while (0)

  // B-fragment = 1.0 in column n==0: row-sum extractor for l.
  const bf16 bv1c = (c16 == 0) ? (bf16)1.0f : (bf16)0.0f;
  bf16x8 bone;
#pragma unroll
  for (int e = 0; e < 8; e++) bone[e] = bv1c;

#pragma unroll 1
  for (int half = 0; half < 2; ++half) {
    const int qi = half ? jb : (31 - jb);         // heavy q-tile first
    const int q0 = qi * 128;

    bf16x8 aq[2][2];
#pragma unroll
    for (int f = 0; f < 2; f++) {
      const int tq = q0 + w * 32 + f * 16 + c16;
      aq[f][0] = *(const bf16x8*)&Qb[((h * SEQ) + tq) * HD + q4 * 8];
      aq[f][1] = *(const bf16x8*)&Qb[((h * SEQ) + tq) * HD + 32 + q4 * 8];
    }
    const int qg[2] = { q0 + w * 32 + c16, q0 + w * 32 + 16 + c16 };  // lane's q-row per f
    const int qb[2] = { q0 + w * 32,       q0 + w * 32 + 16 };        // wave-uniform min q-row
    const int wmax = q0 + w * 32 + 31;            // wave-uniform max q-row

    f32x4 O[2][4];
    f32x4 acc_l[2] = {vzero, vzero};
#pragma unroll
    for (int f = 0; f < 2; f++)
#pragma unroll
      for (int j = 0; j < 4; j++) O[f][j] = vzero;

    const int sEnd = q0 + 64;
    const int sBeg = p * 64;
    if (sBeg <= sEnd) {
      FSTAGE(0, sBeg);
      __syncthreads();                    // tile 0 landed (vmcnt drain)
      int cur = 0;

      for (int s0 = sBeg; s0 <= sEnd; s0 += NPART * 64) {
        const int snext = s0 + NPART * 64;
        if (snext <= sEnd) FSTAGE(cur ^ 1, snext);   // prefetch next tile

        if (s0 <= wmax) {                 // wave-uniform: tile has live rows
          // K fragments: A-operand [m=s][k=d], swizzled cols
          bf16x8 kf0[4], kf1[4];
#pragma unroll
          for (int nt = 0; nt < 4; nt++) {
            kf0[nt] = *(const bf16x8*)&Ks[cur][nt * 16 + c16][(q4 ^ rsw) * 8];
            kf1[nt] = *(const bf16x8*)&Ks[cur][nt * 16 + c16][((q4 + 4) ^ rsw) * 8];
          }
#pragma unroll
          for (int f = 0; f < 2; f++) {
            // S^T tile: D[m=s][n=q]; lane holds q=c16, s=nt*16+q4*4+rg
            f32x4 S[4];
            __builtin_amdgcn_s_setprio(1);
#pragma unroll
            for (int nt = 0; nt < 4; nt++) {
              f32x4 z = vzero;
              z = MFMA_BF16(kf0[nt], aq[f][0], z);
              z = MFMA_BF16(kf1[nt], aq[f][1], z);
              S[nt] = z;
            }
            __builtin_amdgcn_s_setprio(0);
            if (s0 + 63 <= qb[f]) {
              // interior tile: no lane of this wave/f is masked
#pragma unroll
              for (int nt = 0; nt < 4; nt++) {
#pragma unroll
                for (int rg = 0; rg < 4; rg++) S[nt][rg] = exp2f(S[nt][rg]);
                bf16x4 pk = { (bf16)S[nt][0], (bf16)S[nt][1], (bf16)S[nt][2], (bf16)S[nt][3] };
                *(bf16x4*)&Pst[w][f * 16 + c16][nt * 16 + q4 * 4] = pk;
              }
            } else if (s0 > qb[f] + 15) {
              // tile entirely above the diagonal for this wave/f: all masked
              const bf16x4 zk = { (bf16)0.f, (bf16)0.f, (bf16)0.f, (bf16)0.f };
#pragma unroll
              for (int nt = 0; nt < 4; nt++)
                *(bf16x4*)&Pst[w][f * 16 + c16][nt * 16 + q4 * 4] = zk;
            } else {
              // diagonal tile: per-element mask
#pragma unroll
              for (int nt = 0; nt < 4; nt++) {
#pragma unroll
                for (int rg = 0; rg < 4; rg++) {
                  const int s_g = s0 + nt * 16 + q4 * 4 + rg;
                  S[nt][rg] = (s_g > qg[f]) ? 0.f : exp2f(S[nt][rg]);
                }
                bf16x4 pk = { (bf16)S[nt][0], (bf16)S[nt][1], (bf16)S[nt][2], (bf16)S[nt][3] };
                *(bf16x4*)&Pst[w][f * 16 + c16][nt * 16 + q4 * 4] = pk;
              }
            }
          }
          // P fragments (A-op): contiguous b128 from Pst (wave-private)
          bf16x8 ap[2][2];
#pragma unroll
          for (int f = 0; f < 2; f++) {
            ap[f][0] = *(const bf16x8*)&Pst[w][f * 16 + c16][q4 * 8];
            ap[f][1] = *(const bf16x8*)&Pst[w][f * 16 + c16][32 + q4 * 8];
          }
          // row-sum l via ones-column MFMA (matrix pipe, not VALU)
#pragma unroll
          for (int f = 0; f < 2; f++) {
            acc_l[f] = MFMA_BF16(ap[f][0], bone, acc_l[f]);
            acc_l[f] = MFMA_BF16(ap[f][1], bone, acc_l[f]);
          }
#pragma unroll
          for (int dt = 0; dt < 4; dt++) {
            bf16x8 bv0 = *(const bf16x8*)&Vts[cur][dt * 16 + c16][(q4 ^ rsw) * 8];
            bf16x8 bw1 = *(const bf16x8*)&Vts[cur][dt * 16 + c16][((q4 + 4) ^ rsw) * 8];
            __builtin_amdgcn_s_setprio(1);
#pragma unroll
            for (int f = 0; f < 2; f++) {
              O[f][dt] = MFMA_BF16(ap[f][0], bv0, O[f][dt]);
              O[f][dt] = MFMA_BF16(ap[f][1], bw1, O[f][dt]);
            }
            __builtin_amdgcn_s_setprio(0);
          }
        }
        __syncthreads();                  // all waves: next tile landed; reads done
        cur ^= 1;
      }
    }

    const int u = ((h * 32 + qi) * NPART + p);
    bf16* Op = Opart + (size_t)u * 8192;            // 128 x 64
#pragma unroll
    for (int f = 0; f < 2; f++)
#pragma unroll
      for (int dt = 0; dt < 4; dt++)
#pragma unroll
        for (int rg = 0; rg < 4; rg++)
          Op[(w * 32 + f * 16 + q4 * 4 + rg) * 64 + dt * 16 + c16] = (bf16)O[f][dt][rg];
    // l lives in D[q][0]: lanes with c16==0, row q = q4*4+rg.
    if (c16 == 0) {
#pragma unroll
      for (int f = 0; f < 2; f++)
#pragma unroll
        for (int rg = 0; rg < 4; rg++)
          Lpart[u * 128 + w * 32 + f * 16 + q4 * 4 + rg] = acc_l[f][rg];
    }
  }
#undef FSTAGE
}

// ---------------------------------------------------------------------------
// Combine: Y = (sum_p O_p) / (sum_p l_p). Block per 64-row chunk x head.
// ---------------------------------------------------------------------------
__global__ __launch_bounds__(256) void flash_combine(
    const bf16* __restrict__ Opart, const float* __restrict__ Lpart,
    bf16* __restrict__ Y)
{
  const int q64 = blockIdx.x, h = blockIdx.y;
  const int qi = q64 >> 1, roff = (q64 & 1) * 64;
  const int row = threadIdx.x >> 2, cg = (threadIdx.x & 3) * 16;
  const int u0 = (h * 32 + qi) * NPART;
  const int r128 = roff + row;
  float lsum = 0.f;
#pragma unroll
  for (int p = 0; p < NPART; p++) lsum += Lpart[(u0 + p) * 128 + r128];
  const float inv = 1.0f / lsum;
  const bf16* O0 = Opart + (size_t)u0 * 8192 + r128 * 64 + cg;
  bf16* yp = Y + (size_t)(q64 * 64 + row) * DM + h * HD + cg;
#pragma unroll
  for (int j = 0; j < 16; j += 8) {
    float s[8] = {0, 0, 0, 0, 0, 0, 0, 0};
#pragma unroll
    for (int p = 0; p < NPART; p++) {
      bf16x8 a = *(const bf16x8*)(O0 + p * 8192 + j);
#pragma unroll
      for (int e = 0; e < 8; e++) s[e] += (float)a[e];
    }
#pragma unroll
    for (int e = 0; e < 8; e++) yp[j + e] = (bf16)(s[e] * inv);
  }
}

// ---------------------------------------------------------------------------
extern "C" void kernel_launch(void* const* d_in, const int* in_sizes, int n_in,
                              void* d_out, int out_size, void* d_ws, size_t ws_size,
                              hipStream_t stream)
{
  (void)in_sizes; (void)n_in; (void)out_size; (void)ws_size;
  const float* x      = (const float*)d_in[0];
  const float* qkvw   = (const float*)d_in[1];
  const float* cprojw = (const float*)d_in[2];
  float* outp = (float*)d_out;

  const int NX = SEQ * DM, NW = NQKV * DM, NP = DM * DM;

  char* ws = (char*)d_ws;
  bf16*   xb    = (bf16*)(ws);                      // 6,291,456
  bf16*   wqkv  = (bf16*)(ws + 6291456);            // 3,538,944
  bf16*   wproj = (bf16*)(ws + 9830400);            // 1,179,648
  bf16*   Q     = (bf16*)(ws + 11010048);           // 6,291,456
  bf16*   K     = (bf16*)(ws + 17301504);           // 6,291,456
  bf16*   Vt    = (bf16*)(ws + 23592960);           // 6,291,456
  bf16*   Y     = (bf16*)(ws + 29884416);           // 6,291,456
  bf16*   Opart = (bf16*)(ws + 36175872);           // 25,165,824 (1536 x 8192 bf16)
  float*  Lpart = (float*)(ws + 61341696);          //    786,432
  float2* ropeT = (float2*)(ws + 62128128);         //    524,288  (total 62.65 MB)

  const int NCV = (NX + NW + NP) / 2048;            // 2688 convert blocks
  convert_all<<<dim3(NCV + 256), 256, 0, stream>>>(
      x, xb, NX, qkvw, wqkv, NW, cprojw, wproj, NP, ropeT);

  gemm_qkv     <<<dim3(SEQ / 128, NQKV / 128), 256, 0, stream>>>(xb, wqkv, Q, K, Vt, ropeT);
  flash_partial<<<dim3(16 * NH * NPART),       256, 0, stream>>>(Q, K, Vt, Opart, Lpart);
  flash_combine<<<dim3(SEQ / 64, NH),          256, 0, stream>>>(Opart, Lpart, Y);
  gemm_proj    <<<dim3(SEQ / 64, DM / 64),     256, 0, stream>>>(Y, wproj, outp);
}

// Round 16
// 157.144 us; speedup vs baseline: 1.0345x; 1.0236x over previous
//
#include <hip/hip_runtime.h>
#include <math.h>

// Round 28: R27 base (best, 160.8). One change: gemm_proj BK=32 -> BK=64.
// At 64^2/BK=32 proj ran 24 iters of {2 loads, 4 MFMA (~20cyc), 2 barrier
// crossings} — barrier overhead dominated. BK=64: 12 iters, 8 MFMA/iter,
// same total loads, 32KB LDS. Unpadded [64][64] tile uses the R22-proven
// both-sides swizzle: linear gload dest + pre-swizzled source chunk
// ((l&7)^(row&7)) + fragment reads at (q4+ks*4)^(c16&7) — 8 lanes/chunk
// = b128 bank floor; rows r/r+32 share row&7. 32x32 flash MFMA rewrite
// analyzed and rejected: per-tile LDS traffic identical (f/dt amortization
// already achieves the big-fragment reuse), only ~4% issue-cycle saving.

typedef __bf16 bf16;
typedef __bf16 bf16x4 __attribute__((ext_vector_type(4)));
typedef __bf16 bf16x8 __attribute__((ext_vector_type(8)));
typedef float  f32x4  __attribute__((ext_vector_type(4)));

#define MFMA_BF16(a, b, c) __builtin_amdgcn_mfma_f32_16x16x32_bf16((a), (b), (c), 0, 0, 0)

#define SEQ  4096
#define NH   12
#define HD   64
#define DM   768
#define NQKV 2304
#define NPART 4
#define ATTN_SCALE 0.12f
#define LOG2E 1.4426950408889634f
#define RMS_EPS 1.1920928955078125e-07f

typedef __attribute__((address_space(3))) void  lds_void;
typedef const __attribute__((address_space(1))) void g_void;

__device__ __forceinline__ void gload16(const void* g, void* l)
{
  __builtin_amdgcn_global_load_lds((g_void*)g, (lds_void*)l, 16, 0, 0);
}

// ---------------------------------------------------------------------------
// One dispatch: three f32->bf16 conversions + rope LUT (last 256 blocks).
// ---------------------------------------------------------------------------
__global__ __launch_bounds__(256) void convert_all(
    const float* __restrict__ s0, bf16* __restrict__ d0, int n0,
    const float* __restrict__ s1, bf16* __restrict__ d1, int n1,
    const float* __restrict__ s2, bf16* __restrict__ d2, int n2,
    float2* __restrict__ ropeT)
{
  int b = blockIdx.x;
  const int b0 = n0 >> 11, b1 = n1 >> 11, b2 = n2 >> 11;
  if (b >= b0 + b1 + b2) {
    const int idx = (b - (b0 + b1 + b2)) * 256 + threadIdx.x;
    const int m = idx >> 4, c = idx & 15;
    const float fr = exp2f(-10.0f * (float)c * (1.0f / 15.0f));
    float sn, cs;
    sincosf((float)m * fr, &sn, &cs);
    ropeT[idx] = make_float2(cs, sn);
    return;
  }
  const float* s; bf16* d;
  if (b < b0)            { s = s0; d = d0; }
  else if (b < b0 + b1)  { s = s1; d = d1; b -= b0; }
  else                   { s = s2; d = d2; b -= b0 + b1; }
  const int i0 = (b * 256 + threadIdx.x) * 8;
  f32x4 a = *(const f32x4*)(s + i0);
  f32x4 c = *(const f32x4*)(s + i0 + 4);
  bf16x8 o;
#pragma unroll
  for (int j = 0; j < 4; j++) { o[j] = (bf16)a[j]; o[j + 4] = (bf16)c[j]; }
  *(bf16x8*)(d + i0) = o;
}

// ---------------------------------------------------------------------------
// 128x128-tile GEMM core, double-buffered 2-phase (BK=32, 4 waves 2x2).
// ---------------------------------------------------------------------------
__device__ __forceinline__ void gemm128_core(
    const bf16* __restrict__ A, const bf16* __restrict__ B,
    int m0, int n0, bf16 (*As)[128][32], bf16 (*Bs)[128][32], f32x4 acc[4][4])
{
  const int tid = threadIdx.x;
  const int lane = tid & 63, w = tid >> 6;
  const int c16 = lane & 15, q4 = lane >> 4;
  const int mo = (w & 1) * 64, no = (w >> 1) * 64;
  const int srow = tid >> 2, scol = (tid & 3) * 8;   // LDS byte off = tid*16 (lane-linear)
  const f32x4 vzero = {0.f, 0.f, 0.f, 0.f};
#pragma unroll
  for (int i = 0; i < 4; i++)
#pragma unroll
    for (int j = 0; j < 4; j++) acc[i][j] = vzero;

  const bf16* aBase = A + (size_t)(m0 + srow) * DM + scol;
  const bf16* bBase = B + (size_t)(n0 + srow) * DM + scol;

#define STAGE128(buf, kk) do {                                          \
    gload16(aBase + (kk),                   &As[buf][srow][scol]);      \
    gload16(aBase + (size_t)64 * DM + (kk), &As[buf][srow + 64][scol]); \
    gload16(bBase + (kk),                   &Bs[buf][srow][scol]);      \
    gload16(bBase + (size_t)64 * DM + (kk), &Bs[buf][srow + 64][scol]); \
  } while (0)

  STAGE128(0, 0);
  __syncthreads();
  int cur = 0;
  for (int k0 = 0; k0 < DM; k0 += 32) {
    const int kn = k0 + 32;
    if (kn < DM) STAGE128(cur ^ 1, kn);   // prefetch next tile (other buffer)
    bf16x8 ar[4], br[4];
#pragma unroll
    for (int mq = 0; mq < 4; mq++)
      ar[mq] = *(const bf16x8*)&As[cur][mo + mq * 16 + c16][q4 * 8];
#pragma unroll
    for (int nq = 0; nq < 4; nq++)
      br[nq] = *(const bf16x8*)&Bs[cur][no + nq * 16 + c16][q4 * 8];
    __builtin_amdgcn_s_setprio(1);
#pragma unroll
    for (int mq = 0; mq < 4; mq++)
#pragma unroll
      for (int nq = 0; nq < 4; nq++)
        acc[mq][nq] = MFMA_BF16(ar[mq], br[nq], acc[mq][nq]);
    __builtin_amdgcn_s_setprio(0);
    __syncthreads();                      // next tile landed; reads done
    cur ^= 1;
  }
#undef STAGE128
}

// QKV GEMM with FUSED norm+rope epilogue for Q/K (V written transposed raw).
// Q gets ATTN_SCALE * LOG2E folded in so flash can use raw exp2f.
// rope angles from precomputed LUT (one 8B load replaces sincosf).
__global__ __launch_bounds__(256) void gemm_qkv(
    const bf16* __restrict__ A, const bf16* __restrict__ B,
    bf16* __restrict__ Qb, bf16* __restrict__ Kb, bf16* __restrict__ Vt,
    const float2* __restrict__ ropeT)
{
  __shared__ bf16 As[2][128][32];
  __shared__ bf16 Bs[2][128][32];
  const int m0 = blockIdx.x * 128, n0 = blockIdx.y * 128;
  f32x4 acc[4][4];
  gemm128_core(A, B, m0, n0, As, Bs, acc);

  const int lane = threadIdx.x & 63, w = threadIdx.x >> 6;
  const int c16 = lane & 15, q4 = lane >> 4;
  const int mo = (w & 1) * 64, no = (w >> 1) * 64;
  const int kidx = blockIdx.y / 6;
  const int rr0 = (n0 - kidx * DM) + no;     // multiple of 64: one full head
  const int h = rr0 >> 6;

  if (kidx == 2) {
#pragma unroll
    for (int nq = 0; nq < 4; nq++) {
      const int d = nq * 16 + c16;
#pragma unroll
      for (int mq = 0; mq < 4; mq++) {
        const int mb = m0 + mo + mq * 16 + q4 * 4;
#pragma unroll
        for (int rg = 0; rg < 4; rg++)
          Vt[((h * HD) + d) * SEQ + mb + rg] = (bf16)acc[mq][nq][rg];
      }
    }
  } else {
    bf16* dst = kidx ? Kb : Qb;
    const float scale = kidx ? 1.0f : (ATTN_SCALE * LOG2E);
#pragma unroll
    for (int mq = 0; mq < 4; mq++) {
#pragma unroll
      for (int rg = 0; rg < 4; rg++) {
        const int m = m0 + mo + mq * 16 + q4 * 4 + rg;
        const float x0 = acc[mq][0][rg], x1 = acc[mq][1][rg];
        const float x2 = acc[mq][2][rg], x3 = acc[mq][3][rg];
        float ss = x0 * x0 + x1 * x1 + x2 * x2 + x3 * x3;
        ss += __shfl_xor(ss, 1, 64);
        ss += __shfl_xor(ss, 2, 64);
        ss += __shfl_xor(ss, 4, 64);
        ss += __shfl_xor(ss, 8, 64);
        const float rinv = rsqrtf(ss * (1.0f / 64.0f) + RMS_EPS) * scale;
        const float xn0 = x0 * rinv, xn1 = x1 * rinv;
        const float xn2 = x2 * rinv, xn3 = x3 * rinv;
        const float2 t = ropeT[(m << 4) | c16];
        const float cs = t.x, sn = t.y;
        const float y0 = xn0 * cs + xn2 * sn;
        const float y2 = xn2 * cs - xn0 * sn;
        bf16* rp = dst + (size_t)(h * SEQ + m) * HD + c16;
        rp[0]  = (bf16)y0;
        rp[16] = (bf16)xn1;
        rp[32] = (bf16)y2;
        rp[48] = (bf16)xn3;
      }
    }
  }
}

// ---------------------------------------------------------------------------
// 64x64-tile proj GEMM, BK=64, double-buffered 2-phase: 12 iters (halved
// barrier count), 8 MFMA/iter. Unpadded [64][64] tiles: linear gload dest,
// pre-swizzled source chunk ((l&7)^(row&7)), reads at (q4+ks*4)^(c16&7).
// ---------------------------------------------------------------------------
__global__ __launch_bounds__(256) void gemm_proj(
    const bf16* __restrict__ A, const bf16* __restrict__ B, float* __restrict__ C)
{
  __shared__ bf16 As[2][64][64];
  __shared__ bf16 Bs[2][64][64];
  const int m0 = blockIdx.x * 64, n0 = blockIdx.y * 64;
  const int tid = threadIdx.x;
  const int lane = tid & 63, w = tid >> 6;
  const int c16 = lane & 15, q4 = lane >> 4;
  const int mo = (w & 1) * 32, no = (w >> 1) * 32;
  const int srow = w * 8 + (lane >> 3);            // staging row 0..31 (+32 pass 2)
  const int scsw = ((lane & 7) ^ (srow & 7)) * 8;  // pre-swizzled source col (bf16)
  const int sdst = (lane & 7) * 8;                 // linear LDS dest col
  const int rsw = c16 & 7;                         // fragment-read row swizzle
  const f32x4 vzero = {0.f, 0.f, 0.f, 0.f};
  f32x4 acc[2][2];
#pragma unroll
  for (int i = 0; i < 2; i++)
#pragma unroll
    for (int j = 0; j < 2; j++) acc[i][j] = vzero;

  const bf16* aBase = A + (size_t)(m0 + srow) * DM + scsw;
  const bf16* bBase = B + (size_t)(n0 + srow) * DM + scsw;

#define STAGEP(buf, kk) do {                                            \
    gload16(aBase + (kk),                   &As[buf][srow][sdst]);      \
    gload16(aBase + (size_t)32 * DM + (kk), &As[buf][srow + 32][sdst]); \
    gload16(bBase + (kk),                   &Bs[buf][srow][sdst]);      \
    gload16(bBase + (size_t)32 * DM + (kk), &Bs[buf][srow + 32][sdst]); \
  } while (0)

  STAGEP(0, 0);
  __syncthreads();
  int cur = 0;
  for (int k0 = 0; k0 < DM; k0 += 64) {
    const int kn = k0 + 64;
    if (kn < DM) STAGEP(cur ^ 1, kn);
#pragma unroll
    for (int ks = 0; ks < 2; ks++) {
      const int cc = ((q4 + ks * 4) ^ rsw) * 8;
      bf16x8 ar[2], br[2];
#pragma unroll
      for (int mq = 0; mq < 2; mq++)
        ar[mq] = *(const bf16x8*)&As[cur][mo + mq * 16 + c16][cc];
#pragma unroll
      for (int nq = 0; nq < 2; nq++)
        br[nq] = *(const bf16x8*)&Bs[cur][no + nq * 16 + c16][cc];
      __builtin_amdgcn_s_setprio(1);
#pragma unroll
      for (int mq = 0; mq < 2; mq++)
#pragma unroll
        for (int nq = 0; nq < 2; nq++)
          acc[mq][nq] = MFMA_BF16(ar[mq], br[nq], acc[mq][nq]);
      __builtin_amdgcn_s_setprio(0);
    }
    __syncthreads();
    cur ^= 1;
  }
#undef STAGEP

#pragma unroll
  for (int nq = 0; nq < 2; nq++) {
    const int n = n0 + no + nq * 16 + c16;
#pragma unroll
    for (int mq = 0; mq < 2; mq++) {
      const int mb = m0 + mo + mq * 16 + q4 * 4;
#pragma unroll
      for (int rg = 0; rg < 4; rg++)
        C[(size_t)(mb + rg) * DM + n] = acc[mq][nq][rg];
    }
  }
}

// ---------------------------------------------------------------------------
// Flash partial, BM=128, S^T orientation. 2-phase gload_lds staging
// (linear dest + pre-swizzled source), double-buffered, ONE __syncthreads
// per iter. l via ones-column MFMA. Wave-level dead-tile skip.
// 1D grid 768 = 8 XCDs x 96. (Unchanged from R25/R27.)
// ---------------------------------------------------------------------------
__global__ __launch_bounds__(256, 3) void flash_partial(
    const bf16* __restrict__ Qb, const bf16* __restrict__ Kb,
    const bf16* __restrict__ Vt, bf16* __restrict__ Opart,
    float* __restrict__ Lpart)
{
  __shared__ bf16 Ks[2][64][64];
  __shared__ bf16 Vts[2][64][64];
  __shared__ bf16 Pst[4][32][68];                 // [wave][q][s], 8B-pair conflict-free
  const int id = blockIdx.x;                      // 0..767
  const int swz = (id & 7) * 96 + (id >> 3);      // chunked XCD swizzle (768 = 8*96)
  const int h = swz >> 6;                         // 64 works per head (16*NPART)
  const int rrem = swz & 63;
  const int p = rrem >> 4;                        // 0..3
  const int jb = rrem & 15;                       // pair (31-jb, jb)
  const int tid = threadIdx.x;
  const int lane = tid & 63, w = tid >> 6;
  const int c16 = lane & 15, q4 = lane >> 4;
  const int sr = tid >> 3;                        // staging row 0..31
  const int scS = (((tid & 7) ^ (sr & 7))) * 8;   // pre-swizzled source col (bf16)
  const int sdst = (tid & 7) * 8;                 // linear LDS dest col (bf16)
  const int rsw = c16 & 7;                        // fragment-read row swizzle

  const bf16* Kbase = Kb + (size_t)h * SEQ * HD;
  const bf16* Vbase = Vt + (size_t)h * HD * SEQ;
  const f32x4 vzero = {0.f, 0.f, 0.f, 0.f};

#define FSTAGE(buf, ss) do {                                                   \
    gload16(&Kbase[(size_t)((ss) + sr) * HD + scS],       &Ks[buf][sr][sdst]); \
    gload16(&Kbase[(size_t)((ss) + sr + 32) * HD + scS],  &Ks[buf][sr + 32][sdst]); \
    gload16(&Vbase[(size_t)sr * SEQ + (ss) + scS],        &Vts[buf][sr][sdst]); \
    gload16(&Vbase[(size_t)(sr + 32) * SEQ + (ss) + scS], &Vts[buf][sr + 32][sdst]); \
  } while (0)

  // B-fragment = 1.0 in column n==0: row-sum extractor for l.
  const bf16 bv1c = (c16 == 0) ? (bf16)1.0f : (bf16)0.0f;
  bf16x8 bone;
#pragma unroll
  for (int e = 0; e < 8; e++) bone[e] = bv1c;

#pragma unroll 1
  for (int half = 0; half < 2; ++half) {
    const int qi = half ? jb : (31 - jb);         // heavy q-tile first
    const int q0 = qi * 128;

    bf16x8 aq[2][2];
#pragma unroll
    for (int f = 0; f < 2; f++) {
      const int tq = q0 + w * 32 + f * 16 + c16;
      aq[f][0] = *(const bf16x8*)&Qb[((h * SEQ) + tq) * HD + q4 * 8];
      aq[f][1] = *(const bf16x8*)&Qb[((h * SEQ) + tq) * HD + 32 + q4 * 8];
    }
    const int qg[2] = { q0 + w * 32 + c16, q0 + w * 32 + 16 + c16 };  // lane's q-row per f
    const int qb[2] = { q0 + w * 32,       q0 + w * 32 + 16 };        // wave-uniform min q-row
    const int wmax = q0 + w * 32 + 31;            // wave-uniform max q-row

    f32x4 O[2][4];
    f32x4 acc_l[2] = {vzero, vzero};
#pragma unroll
    for (int f = 0; f < 2; f++)
#pragma unroll
      for (int j = 0; j < 4; j++) O[f][j] = vzero;

    const int sEnd = q0 + 64;
    const int sBeg = p * 64;
    if (sBeg <= sEnd) {
      FSTAGE(0, sBeg);
      __syncthreads();                    // tile 0 landed (vmcnt drain)
      int cur = 0;

      for (int s0 = sBeg; s0 <= sEnd; s0 += NPART * 64) {
        const int snext = s0 + NPART * 64;
        if (snext <= sEnd) FSTAGE(cur ^ 1, snext);   // prefetch next tile

        if (s0 <= wmax) {                 // wave-uniform: tile has live rows
          // K fragments: A-operand [m=s][k=d], swizzled cols
          bf16x8 kf0[4], kf1[4];
#pragma unroll
          for (int nt = 0; nt < 4; nt++) {
            kf0[nt] = *(const bf16x8*)&Ks[cur][nt * 16 + c16][(q4 ^ rsw) * 8];
            kf1[nt] = *(const bf16x8*)&Ks[cur][nt * 16 + c16][((q4 + 4) ^ rsw) * 8];
          }
#pragma unroll
          for (int f = 0; f < 2; f++) {
            // S^T tile: D[m=s][n=q]; lane holds q=c16, s=nt*16+q4*4+rg
            f32x4 S[4];
            __builtin_amdgcn_s_setprio(1);
#pragma unroll
            for (int nt = 0; nt < 4; nt++) {
              f32x4 z = vzero;
              z = MFMA_BF16(kf0[nt], aq[f][0], z);
              z = MFMA_BF16(kf1[nt], aq[f][1], z);
              S[nt] = z;
            }
            __builtin_amdgcn_s_setprio(0);
            if (s0 + 63 <= qb[f]) {
              // interior tile: no lane of this wave/f is masked
#pragma unroll
              for (int nt = 0; nt < 4; nt++) {
#pragma unroll
                for (int rg = 0; rg < 4; rg++) S[nt][rg] = exp2f(S[nt][rg]);
                bf16x4 pk = { (bf16)S[nt][0], (bf16)S[nt][1], (bf16)S[nt][2], (bf16)S[nt][3] };
                *(bf16x4*)&Pst[w][f * 16 + c16][nt * 16 + q4 * 4] = pk;
              }
            } else if (s0 > qb[f] + 15) {
              // tile entirely above the diagonal for this wave/f: all masked
              const bf16x4 zk = { (bf16)0.f, (bf16)0.f, (bf16)0.f, (bf16)0.f };
#pragma unroll
              for (int nt = 0; nt < 4; nt++)
                *(bf16x4*)&Pst[w][f * 16 + c16][nt * 16 + q4 * 4] = zk;
            } else {
              // diagonal tile: per-element mask
#pragma unroll
              for (int nt = 0; nt < 4; nt++) {
#pragma unroll
                for (int rg = 0; rg < 4; rg++) {
                  const int s_g = s0 + nt * 16 + q4 * 4 + rg;
                  S[nt][rg] = (s_g > qg[f]) ? 0.f : exp2f(S[nt][rg]);
                }
                bf16x4 pk = { (bf16)S[nt][0], (bf16)S[nt][1], (bf16)S[nt][2], (bf16)S[nt][3] };
                *(bf16x4*)&Pst[w][f * 16 + c16][nt * 16 + q4 * 4] = pk;
              }
            }
          }
          // P fragments (A-op): contiguous b128 from Pst (wave-private)
          bf16x8 ap[2][2];
#pragma unroll
          for (int f = 0; f < 2; f++) {
            ap[f][0] = *(const bf16x8*)&Pst[w][f * 16 + c16][q4 * 8];
            ap[f][1] = *(const bf16x8*)&Pst[w][f * 16 + c16][32 + q4 * 8];
          }
          // row-sum l via ones-column MFMA (matrix pipe, not VALU)
#pragma unroll
          for (int f = 0; f < 2; f++) {
            acc_l[f] = MFMA_BF16(ap[f][0], bone, acc_l[f]);
            acc_l[f] = MFMA_BF16(ap[f][1], bone, acc_l[f]);
          }
#pragma unroll
          for (int dt = 0; dt < 4; dt++) {
            bf16x8 bv0 = *(const bf16x8*)&Vts[cur][dt * 16 + c16][(q4 ^ rsw) * 8];
            bf16x8 bw1 = *(const bf16x8*)&Vts[cur][dt * 16 + c16][((q4 + 4) ^ rsw) * 8];
            __builtin_amdgcn_s_setprio(1);
#pragma unroll
            for (int f = 0; f < 2; f++) {
              O[f][dt] = MFMA_BF16(ap[f][0], bv0, O[f][dt]);
              O[f][dt] = MFMA_BF16(ap[f][1], bw1, O[f][dt]);
            }
            __builtin_amdgcn_s_setprio(0);
          }
        }
        __syncthreads();                  // all waves: next tile landed; reads done
        cur ^= 1;
      }
    }

    const int u = ((h * 32 + qi) * NPART + p);
    bf16* Op = Opart + (size_t)u * 8192;            // 128 x 64
#pragma unroll
    for (int f = 0; f < 2; f++)
#pragma unroll
      for (int dt = 0; dt < 4; dt++)
#pragma unroll
        for (int rg = 0; rg < 4; rg++)
          Op[(w * 32 + f * 16 + q4 * 4 + rg) * 64 + dt * 16 + c16] = (bf16)O[f][dt][rg];
    // l lives in D[q][0]: lanes with c16==0, row q = q4*4+rg.
    if (c16 == 0) {
#pragma unroll
      for (int f = 0; f < 2; f++)
#pragma unroll
        for (int rg = 0; rg < 4; rg++)
          Lpart[u * 128 + w * 32 + f * 16 + q4 * 4 + rg] = acc_l[f][rg];
    }
  }
#undef FSTAGE
}

// ---------------------------------------------------------------------------
// Combine: Y = (sum_p O_p) / (sum_p l_p). Block per 64-row chunk x head.
// ---------------------------------------------------------------------------
__global__ __launch_bounds__(256) void flash_combine(
    const bf16* __restrict__ Opart, const float* __restrict__ Lpart,
    bf16* __restrict__ Y)
{
  const int q64 = blockIdx.x, h = blockIdx.y;
  const int qi = q64 >> 1, roff = (q64 & 1) * 64;
  const int row = threadIdx.x >> 2, cg = (threadIdx.x & 3) * 16;
  const int u0 = (h * 32 + qi) * NPART;
  const int r128 = roff + row;
  float lsum = 0.f;
#pragma unroll
  for (int p = 0; p < NPART; p++) lsum += Lpart[(u0 + p) * 128 + r128];
  const float inv = 1.0f / lsum;
  const bf16* O0 = Opart + (size_t)u0 * 8192 + r128 * 64 + cg;
  bf16* yp = Y + (size_t)(q64 * 64 + row) * DM + h * HD + cg;
#pragma unroll
  for (int j = 0; j < 16; j += 8) {
    float s[8] = {0, 0, 0, 0, 0, 0, 0, 0};
#pragma unroll
    for (int p = 0; p < NPART; p++) {
      bf16x8 a = *(const bf16x8*)(O0 + p * 8192 + j);
#pragma unroll
      for (int e = 0; e < 8; e++) s[e] += (float)a[e];
    }
#pragma unroll
    for (int e = 0; e < 8; e++) yp[j + e] = (bf16)(s[e] * inv);
  }
}

// ---------------------------------------------------------------------------
extern "C" void kernel_launch(void* const* d_in, const int* in_sizes, int n_in,
                              void* d_out, int out_size, void* d_ws, size_t ws_size,
                              hipStream_t stream)
{
  (void)in_sizes; (void)n_in; (void)out_size; (void)ws_size;
  const float* x      = (const float*)d_in[0];
  const float* qkvw   = (const float*)d_in[1];
  const float* cprojw = (const float*)d_in[2];
  float* outp = (float*)d_out;

  const int NX = SEQ * DM, NW = NQKV * DM, NP = DM * DM;

  char* ws = (char*)d_ws;
  bf16*   xb    = (bf16*)(ws);                      // 6,291,456
  bf16*   wqkv  = (bf16*)(ws + 6291456);            // 3,538,944
  bf16*   wproj = (bf16*)(ws + 9830400);            // 1,179,648
  bf16*   Q     = (bf16*)(ws + 11010048);           // 6,291,456
  bf16*   K     = (bf16*)(ws + 17301504);           // 6,291,456
  bf16*   Vt    = (bf16*)(ws + 23592960);           // 6,291,456
  bf16*   Y     = (bf16*)(ws + 29884416);           // 6,291,456
  bf16*   Opart = (bf16*)(ws + 36175872);           // 25,165,824 (1536 x 8192 bf16)
  float*  Lpart = (float*)(ws + 61341696);          //    786,432
  float2* ropeT = (float2*)(ws + 62128128);         //    524,288  (total 62.65 MB)

  const int NCV = (NX + NW + NP) / 2048;            // 2688 convert blocks
  convert_all<<<dim3(NCV + 256), 256, 0, stream>>>(
      x, xb, NX, qkvw, wqkv, NW, cprojw, wproj, NP, ropeT);

  gemm_qkv     <<<dim3(SEQ / 128, NQKV / 128), 256, 0, stream>>>(xb, wqkv, Q, K, Vt, ropeT);
  flash_partial<<<dim3(16 * NH * NPART),       256, 0, stream>>>(Q, K, Vt, Opart, Lpart);
  flash_combine<<<dim3(SEQ / 64, NH),          256, 0, stream>>>(Opart, Lpart, Y);
  gemm_proj    <<<dim3(SEQ / 64, DM / 64),     256, 0, stream>>>(Y, wproj, outp);
}